// Round 1
// baseline (357.946 us; speedup 1.0000x reference)
//
#include <hip/hip_runtime.h>

typedef unsigned int uint;
typedef unsigned short ushort;
typedef __attribute__((ext_vector_type(8))) short  short8;   // 8 bf16 MFMA operand (4 VGPRs)
typedef __attribute__((ext_vector_type(8))) unsigned short u16x8;
typedef __attribute__((ext_vector_type(4))) float  f32x4;    // MFMA accumulator

#define BM 128
#define BN 128
#define BK 32

// round-to-nearest-even f32 -> bf16
__device__ __forceinline__ ushort f2b(float f) {
    uint u = __float_as_uint(f);
    u += 0x7FFFu + ((u >> 16) & 1u);
    return (ushort)(u >> 16);
}

__device__ __forceinline__ void async16(const void* g, void* l) {
    __builtin_amdgcn_global_load_lds(
        (const __attribute__((address_space(1))) void*)g,
        (__attribute__((address_space(3))) void*)l,
        16, 0, 0);
}

// ---------------------------------------------------------------------------
// Kernel 1: expand c (16,16,256) f32 -> Wt bf16 [N=4096][K=4096]
//   Wt[j*256+k][i*256+m] = c[j,i,(k-m)&255]
// one block per (j,i) pair; crev2 is the reversed row duplicated so every
// output row is a contiguous 256-element slice.
// ---------------------------------------------------------------------------
__global__ __launch_bounds__(256) void expand_w(const float* __restrict__ c,
                                                ushort* __restrict__ Wt) {
    const int j = blockIdx.x >> 4;
    const int i = blockIdx.x & 15;
    __shared__ ushort crev2[512];
    const float* cs = c + (size_t)(j * 16 + i) * 256;
    const int t = threadIdx.x;
    {   // crev[mm] = c[(256-mm)&255]  =>  W[k][m] = crev[(m-k)&255]
        ushort b = f2b(cs[(256 - t) & 255]);
        crev2[t] = b;
        crev2[t + 256] = b;
    }
    __syncthreads();
    const int tr = t >> 5;         // 0..7   (row within 8-row group)
    const int tm = (t & 31) * 8;   // 0..248 (col start, 8 elems/thread)
    for (int rb = 0; rb < 256; rb += 8) {
        const int k = rb + tr;
        u16x8 v;
#pragma unroll
        for (int u = 0; u < 8; ++u) v[u] = crev2[tm + u - k + 256];
        *(u16x8*)&Wt[(size_t)(j * 256 + k) * 4096 + i * 256 + tm] = v;
    }
}

// ---------------------------------------------------------------------------
// Kernel 2: x f32 -> bf16, 8 elems/thread, grid-stride
// ---------------------------------------------------------------------------
__global__ __launch_bounds__(256) void conv_x(const float4* __restrict__ x,
                                              u16x8* __restrict__ xb, int n8) {
    int idx = blockIdx.x * blockDim.x + threadIdx.x;
    const int stride = gridDim.x * blockDim.x;
    for (; idx < n8; idx += stride) {
        float4 a = x[idx * 2];
        float4 b = x[idx * 2 + 1];
        u16x8 o;
        o[0] = f2b(a.x); o[1] = f2b(a.y); o[2] = f2b(a.z); o[3] = f2b(a.w);
        o[4] = f2b(b.x); o[5] = f2b(b.y); o[6] = f2b(b.z); o[7] = f2b(b.w);
        xb[idx] = o;
    }
}

// ---------------------------------------------------------------------------
// Kernel 3: GEMM  C[M=8192][N=4096] = A[M][K=4096] * Bt[N][K]^T + bias
// m97 structure: 128x128 tile, BK=32, 4 waves (2x2), global_load_lds width 16,
// mfma_f32_16x16x32_bf16, 2 barriers per K-step.
// ---------------------------------------------------------------------------
__global__ __launch_bounds__(256) void gemm_bt(const ushort* __restrict__ A,
                                               const ushort* __restrict__ Bt,
                                               const float* __restrict__ bias,
                                               float* __restrict__ C) {
    constexpr int M = 8192, N = 4096, K = 4096;
    (void)M;
    __shared__ ushort lA[BM * BK];   // [128][32] bf16, linear (gload_lds dest)
    __shared__ ushort lB[BN * BK];

    const int tid  = threadIdx.x;
    const int bn   = blockIdx.x;     // N/128 = 32
    const int bm   = blockIdx.y;     // M/128 = 64
    const int wave = tid >> 6;
    const int lane = tid & 63;
    const int wr   = wave >> 1;      // 2x2 wave grid, each wave owns 64x64
    const int wc   = wave & 1;
    const int lrow = lane & 15;      // fragment row (A) / col (B)
    const int kgrp = lane >> 4;      // k-offset group: k = kgrp*8 + j

    // staging: thread t covers bytes [t*16, t*16+16) of each 4KB half-tile
    const int srow = tid >> 2;         // 0..63
    const int scol = (tid & 3) * 8;    // element offset within BK
    const ushort* gA = A  + (size_t)(bm * BM + srow) * K + scol;
    const ushort* gB = Bt + (size_t)(bn * BN + srow) * K + scol;
    ushort* sA = &lA[srow * BK + scol];          // = lA + t*8 elems (linear)
    ushort* sB = &lB[srow * BK + scol];

    f32x4 acc[4][4];
#pragma unroll
    for (int m = 0; m < 4; ++m)
#pragma unroll
        for (int n = 0; n < 4; ++n) {
            acc[m][n][0] = 0.f; acc[m][n][1] = 0.f;
            acc[m][n][2] = 0.f; acc[m][n][3] = 0.f;
        }

    for (int kt = 0; kt < K; kt += BK) {
        async16(gA + kt, sA);
        async16(gA + (size_t)64 * K + kt, sA + 64 * BK);
        async16(gB + kt, sB);
        async16(gB + (size_t)64 * K + kt, sB + 64 * BK);
        __syncthreads();   // compiler drains vmcnt(0) before s_barrier

        short8 af[4], bf[4];
#pragma unroll
        for (int m = 0; m < 4; ++m)
            af[m] = *(const short8*)&lA[(wr * 64 + m * 16 + lrow) * BK + kgrp * 8];
#pragma unroll
        for (int n = 0; n < 4; ++n)
            bf[n] = *(const short8*)&lB[(wc * 64 + n * 16 + lrow) * BK + kgrp * 8];
#pragma unroll
        for (int m = 0; m < 4; ++m)
#pragma unroll
            for (int n = 0; n < 4; ++n)
                acc[m][n] = __builtin_amdgcn_mfma_f32_16x16x32_bf16(
                    af[m], bf[n], acc[m][n], 0, 0, 0);
        __syncthreads();
    }

    // epilogue: D row = kgrp*4 + reg, col = lrow  (m89-verified C/D layout)
    float bv[4];
#pragma unroll
    for (int n = 0; n < 4; ++n)
        bv[n] = bias[bn * BN + wc * 64 + n * 16 + lrow];
#pragma unroll
    for (int m = 0; m < 4; ++m) {
        const int row = bm * BM + wr * 64 + m * 16 + kgrp * 4;
#pragma unroll
        for (int n = 0; n < 4; ++n) {
            const int col = bn * BN + wc * 64 + n * 16 + lrow;
#pragma unroll
            for (int r = 0; r < 4; ++r)
                C[(size_t)(row + r) * N + col] = acc[m][n][r] + bv[n];
        }
    }
}

// ---------------------------------------------------------------------------
extern "C" void kernel_launch(void* const* d_in, const int* in_sizes, int n_in,
                              void* d_out, int out_size, void* d_ws, size_t ws_size,
                              hipStream_t stream) {
    const float* x    = (const float*)d_in[0];   // (4,2048,4096) f32
    const float* c    = (const float*)d_in[1];   // (16,16,256) f32
    const float* bias = (const float*)d_in[2];   // (4096,) f32
    float* out = (float*)d_out;                  // (4,2048,4096) f32

    // workspace layout: Wt bf16 (32 MiB) then Xb bf16 (64 MiB) — needs 96 MiB
    ushort* Wb = (ushort*)d_ws;
    ushort* Xb = Wb + (size_t)4096 * 4096;

    hipLaunchKernelGGL(expand_w, dim3(256), dim3(256), 0, stream, c, Wb);
    hipLaunchKernelGGL(conv_x, dim3(2048), dim3(256), 0, stream,
                       (const float4*)x, (u16x8*)Xb, 33554432 / 8);
    hipLaunchKernelGGL(gemm_bt, dim3(32, 64), dim3(256), 0, stream,
                       Xb, Wb, bias, out);
}

// Round 2
// 300.701 us; speedup vs baseline: 1.1904x; 1.1904x over previous
//
#include <hip/hip_runtime.h>

typedef unsigned int uint;
typedef unsigned short ushort;
typedef __attribute__((ext_vector_type(8))) short  short8;   // 8 bf16 (4 VGPRs)
typedef __attribute__((ext_vector_type(8))) unsigned short u16x8;
typedef __attribute__((ext_vector_type(4))) float  f32x4;    // MFMA accumulator

// round-to-nearest-even f32 -> bf16
__device__ __forceinline__ ushort f2b(float f) {
    uint u = __float_as_uint(f);
    u += 0x7FFFu + ((u >> 16) & 1u);
    return (ushort)(u >> 16);
}

__device__ __forceinline__ void async16(const void* g, void* l) {
    __builtin_amdgcn_global_load_lds(
        (const __attribute__((address_space(1))) void*)g,
        (__attribute__((address_space(3))) void*)l,
        16, 0, 0);
}

// ---------------------------------------------------------------------------
// Kernel 1: expand c (16,16,256) f32 -> Wt bf16 [N=4096][K=4096]
//   Wt[j*256+k][i*256+m] = c[j,i,(k-m)&255]
// ---------------------------------------------------------------------------
__global__ __launch_bounds__(256) void expand_w(const float* __restrict__ c,
                                                ushort* __restrict__ Wt) {
    const int j = blockIdx.x >> 4;
    const int i = blockIdx.x & 15;
    __shared__ ushort crev2[512];
    const float* cs = c + (size_t)(j * 16 + i) * 256;
    const int t = threadIdx.x;
    {
        ushort b = f2b(cs[(256 - t) & 255]);
        crev2[t] = b;
        crev2[t + 256] = b;
    }
    __syncthreads();
    const int tr = t >> 5;
    const int tm = (t & 31) * 8;
    for (int rb = 0; rb < 256; rb += 8) {
        const int k = rb + tr;
        u16x8 v;
#pragma unroll
        for (int u = 0; u < 8; ++u) v[u] = crev2[tm + u - k + 256];
        *(u16x8*)&Wt[(size_t)(j * 256 + k) * 4096 + i * 256 + tm] = v;
    }
}

// ---------------------------------------------------------------------------
// Kernel 2: x f32 -> bf16
// ---------------------------------------------------------------------------
__global__ __launch_bounds__(256) void conv_x(const float4* __restrict__ x,
                                              u16x8* __restrict__ xb, int n8) {
    int idx = blockIdx.x * blockDim.x + threadIdx.x;
    const int stride = gridDim.x * blockDim.x;
    for (; idx < n8; idx += stride) {
        float4 a = x[idx * 2];
        float4 b = x[idx * 2 + 1];
        u16x8 o;
        o[0] = f2b(a.x); o[1] = f2b(a.y); o[2] = f2b(a.z); o[3] = f2b(a.w);
        o[4] = f2b(b.x); o[5] = f2b(b.y); o[6] = f2b(b.z); o[7] = f2b(b.w);
        xb[idx] = o;
    }
}

// ---------------------------------------------------------------------------
// Kernel 3: 256x256-tile 8-phase GEMM (T1+T2+T3+T4+T5)
//   C[8192][4096] = A[8192][4096] * Bt[4096][4096]^T + bias
// 512 thr = 8 waves (2M x 4N), per-wave 128x64 out. BK=64, 2 K-tiles/iter.
// LDS 128 KiB: 2 bufs x 4 slots(A0,A1,B0,B1) x [128][64] bf16.
// st_16x32 swizzle: byte ^= ((byte>>9)&1)<<5 -> elem c ^= ((r&4)<<2);
// applied on READ + inverse-applied on the GLOBAL source (linear LDS dest,
// required by global_load_lds).
// ---------------------------------------------------------------------------
template<int MB, int N0>
__device__ __forceinline__ void mm16(f32x4 (&acc)[8][4], short8 (&af)[4][2],
                                     short8 (&bf)[4][2]) {
#pragma unroll
    for (int m = 0; m < 4; ++m)
#pragma unroll
        for (int nn = 0; nn < 2; ++nn)
#pragma unroll
            for (int ks = 0; ks < 2; ++ks)
                acc[MB + m][N0 + nn] = __builtin_amdgcn_mfma_f32_16x16x32_bf16(
                    af[m][ks], bf[N0 + nn][ks], acc[MB + m][N0 + nn], 0, 0, 0);
}

#define BAR()   __builtin_amdgcn_s_barrier()
#define LGKM0() asm volatile("s_waitcnt lgkmcnt(0)" ::: "memory")
#define VMC6()  asm volatile("s_waitcnt vmcnt(6)" ::: "memory")
#define VMC0()  asm volatile("s_waitcnt vmcnt(0)" ::: "memory")
#define PRIO1() __builtin_amdgcn_s_setprio(1)
#define PRIO0() __builtin_amdgcn_s_setprio(0)

__global__ __launch_bounds__(512, 2) void gemm256(const ushort* __restrict__ A,
                                                  const ushort* __restrict__ Bt,
                                                  const float* __restrict__ bias,
                                                  float* __restrict__ C) {
    constexpr int K = 4096, N = 4096;
    __shared__ __align__(16) ushort lds[65536];  // 128 KiB

    const int tid  = threadIdx.x;
    const int wave = tid >> 6;
    const int lane = tid & 63;
    const int wr   = wave >> 2;       // 0..1
    const int wc   = wave & 3;        // 0..3
    const int lrow = lane & 15;
    const int kgrp = lane >> 4;

    // T1: XCD-contiguous block swizzle (512 wgs, 512 % 8 == 0 -> simple form)
    int wg = (int)blockIdx.x;
    wg = (wg & 7) * 64 + (wg >> 3);
    const int bm = wg & 31;           // 32 M-tiles
    const int bn = wg >> 5;           // 16 N-tiles

    // staging: thread t covers linear LDS bytes [t*16,t*16+16) and +8KiB of a
    // 16 KiB half; source col pre-swizzled so linear dest + swizzled read match
    const int r0  = tid >> 3;                              // 0..63
    const int cst = ((tid & 7) << 3) ^ ((r0 & 4) << 2);    // elem col, pre-swz
    const ushort* gA  = A  + (size_t)(bm * 256 + r0) * K + cst;
    const ushort* gB  = Bt + (size_t)(bn * 256 + r0) * K + cst;
    const ushort* gA2 = gA + (size_t)128 * K;
    const ushort* gB2 = gB + (size_t)128 * K;
    const size_t r64 = (size_t)64 * K;

#define STAGE(buf, slot, src, kt) do {                          \
        ushort* d_ = &lds[(buf) * 32768 + (slot) * 8192 + tid * 8]; \
        async16((src) + (kt), d_);                              \
        async16((src) + r64 + (kt), d_ + 4096);                 \
    } while (0)

    // fragment read offset (swizzled): elem = lrow*64 + ks*32 + (kgrp*8 ^ swz)
    const int aoff = lrow * 64 + ((kgrp * 8) ^ ((lrow & 4) << 2));

    f32x4 acc[8][4];
#pragma unroll
    for (int m = 0; m < 8; ++m)
#pragma unroll
        for (int n = 0; n < 4; ++n) acc[m][n] = (f32x4){0.f, 0.f, 0.f, 0.f};

    short8 af[4][2], bf[4][2];

    auto LDA = [&](int base, int half) {   // half 0: rows 0-63, 1: rows 64-127
#pragma unroll
        for (int m = 0; m < 4; ++m)
#pragma unroll
            for (int ks = 0; ks < 2; ++ks)
                af[m][ks] = *(const short8*)&lds[base + wr * 8192 + half * 4096 +
                                                 m * 1024 + ks * 32 + aoff];
    };
    auto LDB = [&](int base) {
#pragma unroll
        for (int n = 0; n < 4; ++n)
#pragma unroll
            for (int ks = 0; ks < 2; ++ks)
                bf[n][ks] = *(const short8*)&lds[base + (2 + (wc >> 1)) * 8192 +
                                                 (wc & 1) * 4096 +
                                                 n * 1024 + ks * 32 + aoff];
    };

    // prologue: tile0 (buf0) fully + tile1 (buf1) 3 of 4 halves; order B0,B1,A0,A1
    STAGE(0, 2, gB, 0);  STAGE(0, 3, gB2, 0);  STAGE(0, 0, gA, 0);  STAGE(0, 1, gA2, 0);
    STAGE(1, 2, gB, 64); STAGE(1, 3, gB2, 64); STAGE(1, 0, gA, 64);
    VMC6();   // 14 issued, wait 8 oldest (= all of tile0)
    BAR();

    for (int it = 0; it < 31; ++it) {
        const int kt2 = it * 128 + 128, kt3 = kt2 + 64, ktn = kt2 - 64;
        // PH1: compute t q(0-3 x 0-1); stage t+1's A1 (last half of t+1)
        LDA(0, 0); LDB(0);
        STAGE(1, 1, gA2, ktn);
        BAR(); LGKM0(); PRIO1(); mm16<0, 0>(acc, af, bf); PRIO0(); BAR();
        // PH2: stage t+2 B0 (B of t fully read in PH1)
        STAGE(0, 2, gB, kt2);
        BAR(); LGKM0(); PRIO1(); mm16<0, 2>(acc, af, bf); PRIO0(); BAR();
        // PH3: read A-high of t; stage t+2 B1
        LDA(0, 1);
        STAGE(0, 3, gB2, kt2);
        BAR(); LGKM0(); PRIO1(); mm16<4, 2>(acc, af, bf); PRIO0(); BAR();
        // PH4: stage t+2 A0; counted vmcnt -> tile t+1 fully landed
        STAGE(0, 0, gA, kt2);
        VMC6();
        BAR(); LGKM0(); PRIO1(); mm16<4, 0>(acc, af, bf); PRIO0(); BAR();
        // PH5: compute t+1 (buf1); stage t+2 A1
        LDA(32768, 0); LDB(32768);
        STAGE(0, 1, gA2, kt2);
        BAR(); LGKM0(); PRIO1(); mm16<0, 0>(acc, af, bf); PRIO0(); BAR();
        // PH6: stage t+3 B0
        STAGE(1, 2, gB, kt3);
        BAR(); LGKM0(); PRIO1(); mm16<0, 2>(acc, af, bf); PRIO0(); BAR();
        // PH7: stage t+3 B1
        LDA(32768, 1);
        STAGE(1, 3, gB2, kt3);
        BAR(); LGKM0(); PRIO1(); mm16<4, 2>(acc, af, bf); PRIO0(); BAR();
        // PH8: stage t+3 A0; counted vmcnt -> tile t+2 fully landed
        STAGE(1, 0, gA, kt3);
        VMC6();
        BAR(); LGKM0(); PRIO1(); mm16<4, 0>(acc, af, bf); PRIO0(); BAR();
    }

    // final iteration: tiles 62 (buf0, kt=3968) and 63 (buf1, kt=4032)
    {
        LDA(0, 0); LDB(0);
        STAGE(1, 1, gA2, 4032);      // last half of tile 63
        BAR(); LGKM0(); PRIO1(); mm16<0, 0>(acc, af, bf); PRIO0(); BAR();
        BAR(); LGKM0(); PRIO1(); mm16<0, 2>(acc, af, bf); PRIO0(); BAR();
        LDA(0, 1);
        BAR(); LGKM0(); PRIO1(); mm16<4, 2>(acc, af, bf); PRIO0(); BAR();
        VMC0();                       // drain: tile 63 fully landed
        BAR(); LGKM0(); PRIO1(); mm16<4, 0>(acc, af, bf); PRIO0(); BAR();
        LDA(32768, 0); LDB(32768);
        LGKM0(); PRIO1(); mm16<0, 0>(acc, af, bf); PRIO0();
        PRIO1(); mm16<0, 2>(acc, af, bf); PRIO0();
        LDA(32768, 1);
        LGKM0(); PRIO1(); mm16<4, 2>(acc, af, bf); PRIO0();
        PRIO1(); mm16<4, 0>(acc, af, bf); PRIO0();
    }

    // epilogue: D row = kgrp*4 + reg, col = lrow (verified m89 layout)
    const int colbase = bn * 256 + wc * 64 + lrow;
    float bv[4];
#pragma unroll
    for (int n = 0; n < 4; ++n) bv[n] = bias[colbase + n * 16];
    const int rowbase = bm * 256 + wr * 128 + kgrp * 4;
#pragma unroll
    for (int m = 0; m < 8; ++m)
#pragma unroll
        for (int n = 0; n < 4; ++n) {
            const size_t base = (size_t)(rowbase + m * 16) * N + colbase + n * 16;
#pragma unroll
            for (int r = 0; r < 4; ++r)
                C[base + (size_t)r * N] = acc[m][n][r] + bv[n];
        }
#undef STAGE
}

// ---------------------------------------------------------------------------
extern "C" void kernel_launch(void* const* d_in, const int* in_sizes, int n_in,
                              void* d_out, int out_size, void* d_ws, size_t ws_size,
                              hipStream_t stream) {
    const float* x    = (const float*)d_in[0];   // (4,2048,4096) f32
    const float* c    = (const float*)d_in[1];   // (16,16,256) f32
    const float* bias = (const float*)d_in[2];   // (4096,) f32
    float* out = (float*)d_out;                  // (4,2048,4096) f32

    ushort* Wb = (ushort*)d_ws;                  // 32 MiB
    ushort* Xb = Wb + (size_t)4096 * 4096;       // 64 MiB

    hipLaunchKernelGGL(expand_w, dim3(256), dim3(256), 0, stream, c, Wb);
    hipLaunchKernelGGL(conv_x, dim3(2048), dim3(256), 0, stream,
                       (const float4*)x, (u16x8*)Xb, 33554432 / 8);
    hipLaunchKernelGGL(gemm256, dim3(512), dim3(512), 0, stream,
                       Xb, Wb, bias, out);
}

// Round 3
// 273.814 us; speedup vs baseline: 1.3073x; 1.0982x over previous
//
#include <hip/hip_runtime.h>

typedef unsigned int uint;
typedef unsigned short ushort;
typedef __attribute__((ext_vector_type(8))) short  short8;   // 8 bf16 (4 VGPRs)
typedef __attribute__((ext_vector_type(8))) unsigned short u16x8;
typedef __attribute__((ext_vector_type(4))) float  f32x4;    // MFMA accumulator

// round-to-nearest-even f32 -> bf16
__device__ __forceinline__ ushort f2b(float f) {
    uint u = __float_as_uint(f);
    u += 0x7FFFu + ((u >> 16) & 1u);
    return (ushort)(u >> 16);
}

__device__ __forceinline__ void async16(const void* g, void* l) {
    __builtin_amdgcn_global_load_lds(
        (const __attribute__((address_space(1))) void*)g,
        (__attribute__((address_space(3))) void*)l,
        16, 0, 0);
}

// ---------------------------------------------------------------------------
// Kernel 1: expand c (16,16,256) f32 -> Wt bf16 [N=4096][K=4096]
//   Wt[j*256+k][i*256+m] = c[j,i,(k-m)&255]
// ---------------------------------------------------------------------------
__global__ __launch_bounds__(256) void expand_w(const float* __restrict__ c,
                                                ushort* __restrict__ Wt) {
    const int j = blockIdx.x >> 4;
    const int i = blockIdx.x & 15;
    __shared__ ushort crev2[512];
    const float* cs = c + (size_t)(j * 16 + i) * 256;
    const int t = threadIdx.x;
    {
        ushort b = f2b(cs[(256 - t) & 255]);
        crev2[t] = b;
        crev2[t + 256] = b;
    }
    __syncthreads();
    const int tr = t >> 5;
    const int tm = (t & 31) * 8;
    for (int rb = 0; rb < 256; rb += 8) {
        const int k = rb + tr;
        u16x8 v;
#pragma unroll
        for (int u = 0; u < 8; ++u) v[u] = crev2[tm + u - k + 256];
        *(u16x8*)&Wt[(size_t)(j * 256 + k) * 4096 + i * 256 + tm] = v;
    }
}

// ---------------------------------------------------------------------------
// Kernel 2: x f32 -> bf16
// ---------------------------------------------------------------------------
__global__ __launch_bounds__(256) void conv_x(const float4* __restrict__ x,
                                              u16x8* __restrict__ xb, int n8) {
    int idx = blockIdx.x * blockDim.x + threadIdx.x;
    const int stride = gridDim.x * blockDim.x;
    for (; idx < n8; idx += stride) {
        float4 a = x[idx * 2];
        float4 b = x[idx * 2 + 1];
        u16x8 o;
        o[0] = f2b(a.x); o[1] = f2b(a.y); o[2] = f2b(a.z); o[3] = f2b(a.w);
        o[4] = f2b(b.x); o[5] = f2b(b.y); o[6] = f2b(b.z); o[7] = f2b(b.w);
        xb[idx] = o;
    }
}

// ---------------------------------------------------------------------------
// Kernel 3: 256x256-tile 8-phase GEMM (T1+T2+T3+T4+T5)
//   C[8192][4096] = A[8192][4096] * Bt[4096][4096]^T + bias
// 512 thr = 8 waves (2M x 4N), per-wave 128x64 out. BK=64, 2 K-tiles/iter.
// LDS 128 KiB: 2 bufs x 4 slots(A0,A1,B0,B1) x [128][64] bf16.
// T2 swizzle (3-bit): 16B-slot s' = s ^ (row&7). Applied as inverse on the
// GLOBAL source (linear LDS dest, required by global_load_lds) + same XOR on
// the ds_read col. 2 lanes/bank residual = free (m136).
// ---------------------------------------------------------------------------
template<int MB, int N0>
__device__ __forceinline__ void mm16(f32x4 (&acc)[8][4], short8 (&af)[4][2],
                                     short8 (&bf)[4][2]) {
#pragma unroll
    for (int m = 0; m < 4; ++m)
#pragma unroll
        for (int nn = 0; nn < 2; ++nn)
#pragma unroll
            for (int ks = 0; ks < 2; ++ks)
                acc[MB + m][N0 + nn] = __builtin_amdgcn_mfma_f32_16x16x32_bf16(
                    af[m][ks], bf[N0 + nn][ks], acc[MB + m][N0 + nn], 0, 0, 0);
}

#define BAR()   __builtin_amdgcn_s_barrier()
#define LGKM0() asm volatile("s_waitcnt lgkmcnt(0)" ::: "memory")
#define VMC6()  asm volatile("s_waitcnt vmcnt(6)" ::: "memory")
#define VMC0()  asm volatile("s_waitcnt vmcnt(0)" ::: "memory")
#define PRIO1() __builtin_amdgcn_s_setprio(1)
#define PRIO0() __builtin_amdgcn_s_setprio(0)

__global__ __launch_bounds__(512, 2) void gemm256(const ushort* __restrict__ A,
                                                  const ushort* __restrict__ Bt,
                                                  const float* __restrict__ bias,
                                                  float* __restrict__ C) {
    constexpr int K = 4096, N = 4096;
    __shared__ __align__(16) ushort lds[65536];  // 128 KiB

    const int tid  = threadIdx.x;
    const int wave = tid >> 6;
    const int lane = tid & 63;
    const int wr   = wave >> 2;       // 0..1
    const int wc   = wave & 3;        // 0..3
    const int lrow = lane & 15;
    const int kgrp = lane >> 4;

    // T1: XCD 8x8-square swizzle. Block wg runs on XCD wg&7; give each XCD a
    // contiguous 8bm x 8bn square (32 MB working set vs 68 MB with stripes).
    {
    }
    const int wg  = (int)blockIdx.x;
    const int xcd = wg & 7;
    const int idx = wg >> 3;
    const int bm  = (xcd & 3) * 8 + (idx & 7);   // 32 M-tiles
    const int bn  = (xcd >> 2) * 8 + (idx >> 3); // 16 N-tiles

    // staging: thread t covers linear LDS bytes [t*16,t*16+16) (+8KiB) of a
    // 16 KiB half; source col carries the inverse swizzle
    const int r0  = tid >> 3;                              // 0..63
    const int cst = ((tid & 7) << 3) ^ ((r0 & 7) << 3);    // elem col, pre-swz
    const ushort* gA  = A  + (size_t)(bm * 256 + r0) * K + cst;
    const ushort* gB  = Bt + (size_t)(bn * 256 + r0) * K + cst;
    const ushort* gA2 = gA + (size_t)128 * K;
    const ushort* gB2 = gB + (size_t)128 * K;
    const size_t r64 = (size_t)64 * K;

#define STAGE(buf, slot, src, kt) do {                          \
        ushort* d_ = &lds[(buf) * 32768 + (slot) * 8192 + tid * 8]; \
        async16((src) + (kt), d_);                              \
        async16((src) + r64 + (kt), d_ + 4096);                 \
    } while (0)

    const int swz = (lrow & 7) << 3;   // 3-bit read swizzle (elems)

    f32x4 acc[8][4];
#pragma unroll
    for (int m = 0; m < 8; ++m)
#pragma unroll
        for (int n = 0; n < 4; ++n) acc[m][n] = (f32x4){0.f, 0.f, 0.f, 0.f};

    short8 af[4][2], bf[4][2];

    auto LDA = [&](int base, int half) {   // half 0: rows 0-63, 1: rows 64-127
#pragma unroll
        for (int m = 0; m < 4; ++m)
#pragma unroll
            for (int ks = 0; ks < 2; ++ks)
                af[m][ks] = *(const short8*)&lds[base + wr * 8192 + half * 4096 +
                                                 m * 1024 + lrow * 64 +
                                                 ((ks * 32 + kgrp * 8) ^ swz)];
    };
    auto LDB = [&](int base) {
#pragma unroll
        for (int n = 0; n < 4; ++n)
#pragma unroll
            for (int ks = 0; ks < 2; ++ks)
                bf[n][ks] = *(const short8*)&lds[base + (2 + (wc >> 1)) * 8192 +
                                                 (wc & 1) * 4096 +
                                                 n * 1024 + lrow * 64 +
                                                 ((ks * 32 + kgrp * 8) ^ swz)];
    };

    // prologue: tile0 (buf0) fully + tile1 (buf1) 3 of 4 halves; order B0,B1,A0,A1
    STAGE(0, 2, gB, 0);  STAGE(0, 3, gB2, 0);  STAGE(0, 0, gA, 0);  STAGE(0, 1, gA2, 0);
    STAGE(1, 2, gB, 64); STAGE(1, 3, gB2, 64); STAGE(1, 0, gA, 64);
    VMC6();   // 14 issued, wait 8 oldest (= all of tile0)
    BAR();

    for (int it = 0; it < 31; ++it) {
        const int kt2 = it * 128 + 128, kt3 = kt2 + 64, ktn = kt2 - 64;
        // PH1: compute t q(0-3 x 0-1); stage t+1's A1 (last half of t+1)
        LDA(0, 0); LDB(0);
        STAGE(1, 1, gA2, ktn);
        BAR(); LGKM0(); PRIO1(); mm16<0, 0>(acc, af, bf); PRIO0(); BAR();
        // PH2: stage t+2 B0 (B of t fully read in PH1)
        STAGE(0, 2, gB, kt2);
        BAR(); LGKM0(); PRIO1(); mm16<0, 2>(acc, af, bf); PRIO0(); BAR();
        // PH3: read A-high of t; stage t+2 B1
        LDA(0, 1);
        STAGE(0, 3, gB2, kt2);
        BAR(); LGKM0(); PRIO1(); mm16<4, 2>(acc, af, bf); PRIO0(); BAR();
        // PH4: stage t+2 A0; counted vmcnt -> tile t+1 fully landed
        STAGE(0, 0, gA, kt2);
        VMC6();
        BAR(); LGKM0(); PRIO1(); mm16<4, 0>(acc, af, bf); PRIO0(); BAR();
        // PH5: compute t+1 (buf1); stage t+2 A1
        LDA(32768, 0); LDB(32768);
        STAGE(0, 1, gA2, kt2);
        BAR(); LGKM0(); PRIO1(); mm16<0, 0>(acc, af, bf); PRIO0(); BAR();
        // PH6: stage t+3 B0
        STAGE(1, 2, gB, kt3);
        BAR(); LGKM0(); PRIO1(); mm16<0, 2>(acc, af, bf); PRIO0(); BAR();
        // PH7: stage t+3 B1
        LDA(32768, 1);
        STAGE(1, 3, gB2, kt3);
        BAR(); LGKM0(); PRIO1(); mm16<4, 2>(acc, af, bf); PRIO0(); BAR();
        // PH8: stage t+3 A0; counted vmcnt -> tile t+2 fully landed
        STAGE(1, 0, gA, kt3);
        VMC6();
        BAR(); LGKM0(); PRIO1(); mm16<4, 0>(acc, af, bf); PRIO0(); BAR();
    }

    // final iteration: tiles 62 (buf0, kt=3968) and 63 (buf1, kt=4032)
    {
        LDA(0, 0); LDB(0);
        STAGE(1, 1, gA2, 4032);      // last half of tile 63
        BAR(); LGKM0(); PRIO1(); mm16<0, 0>(acc, af, bf); PRIO0(); BAR();
        BAR(); LGKM0(); PRIO1(); mm16<0, 2>(acc, af, bf); PRIO0(); BAR();
        LDA(0, 1);
        BAR(); LGKM0(); PRIO1(); mm16<4, 2>(acc, af, bf); PRIO0(); BAR();
        VMC0();                       // drain: tile 63 fully landed
        BAR(); LGKM0(); PRIO1(); mm16<4, 0>(acc, af, bf); PRIO0(); BAR();
        LDA(32768, 0); LDB(32768);
        LGKM0(); PRIO1(); mm16<0, 0>(acc, af, bf); PRIO0();
        PRIO1(); mm16<0, 2>(acc, af, bf); PRIO0();
        LDA(32768, 1);
        LGKM0(); PRIO1(); mm16<4, 2>(acc, af, bf); PRIO0();
        PRIO1(); mm16<4, 0>(acc, af, bf); PRIO0();
    }

    // epilogue: D row = kgrp*4 + reg, col = lrow (verified m89 layout)
    const int colbase = bn * 256 + wc * 64 + lrow;
    float bv[4];
#pragma unroll
    for (int n = 0; n < 4; ++n) bv[n] = bias[colbase + n * 16];
    const int rowbase = bm * 256 + wr * 128 + kgrp * 4;
#pragma unroll
    for (int m = 0; m < 8; ++m)
#pragma unroll
        for (int n = 0; n < 4; ++n) {
            const size_t base = (size_t)(rowbase + m * 16) * N + colbase + n * 16;
#pragma unroll
            for (int r = 0; r < 4; ++r)
                C[base + (size_t)r * N] = acc[m][n][r] + bv[n];
        }
#undef STAGE
}

// ---------------------------------------------------------------------------
extern "C" void kernel_launch(void* const* d_in, const int* in_sizes, int n_in,
                              void* d_out, int out_size, void* d_ws, size_t ws_size,
                              hipStream_t stream) {
    const float* x    = (const float*)d_in[0];   // (4,2048,4096) f32
    const float* c    = (const float*)d_in[1];   // (16,16,256) f32
    const float* bias = (const float*)d_in[2];   // (4096,) f32
    float* out = (float*)d_out;                  // (4,2048,4096) f32

    ushort* Wb = (ushort*)d_ws;                  // 32 MiB
    ushort* Xb = Wb + (size_t)4096 * 4096;       // 64 MiB

    hipLaunchKernelGGL(expand_w, dim3(256), dim3(256), 0, stream, c, Wb);
    hipLaunchKernelGGL(conv_x, dim3(2048), dim3(256), 0, stream,
                       (const float4*)x, (u16x8*)Xb, 33554432 / 8);
    hipLaunchKernelGGL(gemm256, dim3(512), dim3(512), 0, stream,
                       Xb, Wb, bias, out);
}